// Round 2
// baseline (1081.528 us; speedup 1.0000x reference)
//
#include <hip/hip_runtime.h>
#include <stdint.h>

#define T_TOK 1024
#define HD 2880
#define ID 2880
#define NE 16
#define NTOP 4

#define BM 128
#define BN 64
#define BK 64
#define NKT (HD / BK)        // 45
#define NIB (ID / BN)        // 45
#define NMB (T_TOK / BM)     // 8
#define NB1 (NE * NIB * NMB) // 5760

typedef short bf16x8 __attribute__((ext_vector_type(8)));
typedef float f32x4 __attribute__((ext_vector_type(4)));

// fp32 -> bf16 (RNE) via native __bf16 cast: compiler emits v_cvt_pk_bf16_f32
__device__ __forceinline__ uint4 pack8f(const float* v) {
    union { __bf16 b[8]; uint4 q; } p;
#pragma unroll
    for (int j = 0; j < 8; j++) p.b[j] = (__bf16)v[j];
    return p.q;
}
__device__ __forceinline__ unsigned short bf16bits(float f) {
    union { __bf16 b[2]; unsigned short u[2]; } p;
    p.b[0] = (__bf16)f;
    return p.u[0];
}

// ---------------- init: zero output + counts ----------------
__global__ __launch_bounds__(256) void k_init(float* __restrict__ out, int* __restrict__ cnt) {
    int i = blockIdx.x * 256 + threadIdx.x;
    ((float4*)out)[i] = make_float4(0.f, 0.f, 0.f, 0.f);
    if (blockIdx.x == 0 && threadIdx.x < NE) cnt[threadIdx.x] = 0;
}

// ---------------- router ----------------
__global__ __launch_bounds__(256) void k_router(
    const float* __restrict__ x, const float* __restrict__ rw, const float* __restrict__ rb,
    float* __restrict__ topw, int* __restrict__ cnt, int* __restrict__ list)
{
    const int t = blockIdx.x;
    const int tid = threadIdx.x;
    float acc[NE];
#pragma unroll
    for (int e = 0; e < NE; e++) acc[e] = 0.f;
    for (int c = tid; c < HD; c += 256) {
        float xv = x[(size_t)t * HD + c];
#pragma unroll
        for (int e = 0; e < NE; e++) acc[e] += xv * rw[(size_t)e * HD + c];
    }
    __shared__ float red[4][NE];
    const int lane = tid & 63, wv = tid >> 6;
#pragma unroll
    for (int e = 0; e < NE; e++) {
        float v = acc[e];
#pragma unroll
        for (int off = 32; off > 0; off >>= 1) v += __shfl_down(v, off, 64);
        if (lane == 0) red[wv][e] = v;
    }
    __syncthreads();
    if (tid == 0) {
        float p[NE];
        float mx = -1e30f;
        for (int e = 0; e < NE; e++) {
            float v = red[0][e] + red[1][e] + red[2][e] + red[3][e] + rb[e];
            p[e] = v; mx = fmaxf(mx, v);
        }
        for (int e = 0; e < NE; e++) p[e] = expf(p[e] - mx);
        int sel[NTOP]; float pw[NTOP]; float ssum = 0.f;
        for (int k = 0; k < NTOP; k++) {
            float best = -1.f; int bi = 0;
            for (int e = 0; e < NE; e++)
                if (p[e] > best) { best = p[e]; bi = e; }
            sel[k] = bi; pw[k] = best; ssum += best; p[bi] = -2.f;
        }
        for (int k = 0; k < NTOP; k++) {
            topw[t * NTOP + k] = pw[k] / ssum;
            int e = sel[k];
            int pos = atomicAdd(&cnt[e], 1);
            list[e * T_TOK + pos] = t * NTOP + k;
        }
    }
}

// ---------------- prefix scan ----------------
__global__ void k_scan(const int* __restrict__ cnt, int* __restrict__ offs) {
    if (threadIdx.x == 0 && blockIdx.x == 0) {
        int s = 0;
        for (int e = 0; e < NE; e++) { offs[e] = s; s += cnt[e]; }
        offs[NE] = s;
    }
}

// ---------------- GEMM1: pipelined, double-buffered ----------------
__global__ __launch_bounds__(512) void k_gemm1(
    const float* __restrict__ x,
    const float* __restrict__ wg, const float* __restrict__ bg,
    const float* __restrict__ wu, const float* __restrict__ bu,
    const int* __restrict__ cnt, const int* __restrict__ offs,
    const int* __restrict__ list,
    unsigned short* __restrict__ act)
{
    // XCD-aware swizzle (m204 bijective, NB1 % 8 == 0), m innermost in logical order
    const int lin = blockIdx.x;
    const int logical = (lin & 7) * (NB1 / 8) + (lin >> 3);
    const int mblk = logical & 7;
    const int iblk = (logical >> 3) % NIB;
    const int e = logical / (NIB * NMB);

    const int count = cnt[e];
    const int m0 = mblk * BM;
    if (m0 >= count) return;
    const int mcount = min(BM, count - m0);
    const int i0 = iblk * BN;
    const int tid = threadIdx.x;

    __shared__ char sA[2][BM * BK * 2];   // 16 KB x2
    __shared__ char sG[2][BN * BK * 2];   // 8 KB x2
    __shared__ char sU[2][BN * BK * 2];   // 8 KB x2
    __shared__ int lidx[BM];

    if (tid < BM) lidx[tid] = list[e * T_TOK + m0 + min(tid, mcount - 1)];
    __syncthreads();

    // A staging: 4 threads/row, 16 floats each
    const int ar = tid >> 2, acg = tid & 3;
    const float* asrc = x + (size_t)(lidx[ar] >> 2) * HD + acg * 16;

    // W staging: tid<256 -> gate, else up; 64 i-cols x 4 h-groups of 16
    const int wtid = tid & 255;
    const int wc = wtid & 63, whg = wtid >> 6;
    const float* wsrc = (tid < 256 ? wg : wu) + ((size_t)e * HD + whg * 16) * ID + i0 + wc;
    char* const wdst0 = (tid < 256 ? sG[0] : sU[0]);
    char* const wdst1 = (tid < 256 ? sG[1] : sU[1]);

    const int lane = tid & 63, wid = tid >> 6;
    const int wm = wid >> 1, wn = wid & 1;
    const int lr = lane & 15, lk = lane >> 4;

    float4 ra[4];
    float rwv[16];

#define LOAD1(kt) do { \
        const float* s_ = asrc + (kt) * BK; \
        ra[0] = ((const float4*)s_)[0]; ra[1] = ((const float4*)s_)[1]; \
        ra[2] = ((const float4*)s_)[2]; ra[3] = ((const float4*)s_)[3]; \
        const float* w_ = wsrc + (size_t)(kt) * BK * ID; \
        _Pragma("unroll") \
        for (int j_ = 0; j_ < 16; j_++) rwv[j_] = w_[(size_t)j_ * ID]; \
    } while (0)

#define STORE1(buf) do { \
        float v_[16]; \
        _Pragma("unroll") \
        for (int p_ = 0; p_ < 4; p_++) { \
            v_[p_ * 4 + 0] = ra[p_].x; v_[p_ * 4 + 1] = ra[p_].y; \
            v_[p_ * 4 + 2] = ra[p_].z; v_[p_ * 4 + 3] = ra[p_].w; \
        } \
        *(uint4*)(sA[buf] + ar * 128 + (((acg * 2) ^ (ar & 7)) * 16)) = pack8f(v_); \
        *(uint4*)(sA[buf] + ar * 128 + (((acg * 2 + 1) ^ (ar & 7)) * 16)) = pack8f(v_ + 8); \
        char* wd_ = (buf) ? wdst1 : wdst0; \
        *(uint4*)(wd_ + wc * 128 + (((whg * 2) ^ (wc & 7)) * 16)) = pack8f(rwv); \
        *(uint4*)(wd_ + wc * 128 + (((whg * 2 + 1) ^ (wc & 7)) * 16)) = pack8f(rwv + 8); \
    } while (0)

    f32x4 accG[2][2], accU[2][2];
#pragma unroll
    for (int mb = 0; mb < 2; mb++)
#pragma unroll
        for (int cb = 0; cb < 2; cb++) {
            accG[mb][cb] = (f32x4){0.f, 0.f, 0.f, 0.f};
            accU[mb][cb] = (f32x4){0.f, 0.f, 0.f, 0.f};
        }

    LOAD1(0);
    STORE1(0);
    __syncthreads();

    for (int kt = 0; kt < NKT; kt++) {
        const int cur = kt & 1;
        const bool more = (kt + 1 < NKT);
        if (more) LOAD1(kt + 1);          // in flight during MFMA
        const char* cA = sA[cur];
        const char* cG = sG[cur];
        const char* cU = sU[cur];
#pragma unroll
        for (int ks = 0; ks < 2; ks++) {
            const int s = ks * 4 + lk;
            bf16x8 af[2], gf[2], uf[2];
#pragma unroll
            for (int mb = 0; mb < 2; mb++) {
                int rr = wm * 32 + mb * 16 + lr;
                af[mb] = *(const bf16x8*)(cA + rr * 128 + ((s ^ (rr & 7)) * 16));
            }
#pragma unroll
            for (int cb = 0; cb < 2; cb++) {
                int ii = wn * 32 + cb * 16 + lr;
                gf[cb] = *(const bf16x8*)(cG + ii * 128 + ((s ^ (ii & 7)) * 16));
                uf[cb] = *(const bf16x8*)(cU + ii * 128 + ((s ^ (ii & 7)) * 16));
            }
#pragma unroll
            for (int mb = 0; mb < 2; mb++)
#pragma unroll
                for (int cb = 0; cb < 2; cb++) {
                    accG[mb][cb] = __builtin_amdgcn_mfma_f32_16x16x32_bf16(af[mb], gf[cb], accG[mb][cb], 0, 0, 0);
                    accU[mb][cb] = __builtin_amdgcn_mfma_f32_16x16x32_bf16(af[mb], uf[cb], accU[mb][cb], 0, 0, 0);
                }
        }
        if (more) STORE1(cur ^ 1);        // convert + write next tile
        __syncthreads();
    }
#undef LOAD1
#undef STORE1

    const int gbase = offs[e] + m0;
#pragma unroll
    for (int mb = 0; mb < 2; mb++)
#pragma unroll
        for (int cb = 0; cb < 2; cb++) {
            const int col = i0 + wn * 32 + cb * 16 + lr;
            const float bgv = bg[e * ID + col];
            const float buv = bu[e * ID + col];
#pragma unroll
            for (int q = 0; q < 4; q++) {
                const int r = wm * 32 + mb * 16 + lk * 4 + q;
                if (r < mcount) {
                    float gv = fminf(accG[mb][cb][q] + bgv, 7.0f);
                    float uv = fminf(fmaxf(accU[mb][cb][q] + buv, -7.0f), 7.0f);
                    float av = (uv + 1.0f) * (gv / (1.0f + __expf(-1.702f * gv)));
                    act[(size_t)(gbase + r) * ID + col] = bf16bits(av);
                }
            }
        }
}

// ---------------- GEMM2: pipelined, double-buffered ----------------
__global__ __launch_bounds__(512) void k_gemm2(
    const unsigned short* __restrict__ act,
    const float* __restrict__ wd, const float* __restrict__ bd,
    const float* __restrict__ topw,
    const int* __restrict__ cnt, const int* __restrict__ offs,
    const int* __restrict__ list,
    float* __restrict__ out)
{
    const int lin = blockIdx.x;
    const int logical = (lin & 7) * (NB1 / 8) + (lin >> 3);
    const int mblk = logical & 7;
    const int hblk = (logical >> 3) % NIB;
    const int e = logical / (NIB * NMB);

    const int count = cnt[e];
    const int m0 = mblk * BM;
    if (m0 >= count) return;
    const int mcount = min(BM, count - m0);
    const int h0 = hblk * BN;
    const int tid = threadIdx.x;
    const int gbase = offs[e] + m0;

    __shared__ char sA[2][BM * BK * 2];   // 16 KB x2
    __shared__ char sW[2][BN * BK * 2];   // 8 KB x2
    __shared__ int lidx[BM];

    if (tid < BM) lidx[tid] = list[e * T_TOK + m0 + min(tid, mcount - 1)];
    __syncthreads();

    const int ar = tid >> 2, acg = tid & 3;
    const int arow = gbase + min(ar, mcount - 1);
    const unsigned short* asrc = act + (size_t)arow * ID + acg * 16;

    const int wc = tid & 63, whg = tid >> 6;        // 8 k-groups of 8
    const float* wsrc = wd + (size_t)e * ID * HD + (size_t)(whg * 8) * HD + h0 + wc;

    const int lane = tid & 63, wid = tid >> 6;
    const int wm = wid >> 1, wn = wid & 1;
    const int lr = lane & 15, lk = lane >> 4;

    uint4 ra0, ra1;
    float rwv[8];

#define LOAD2(kt) do { \
        const uint4* s_ = (const uint4*)(asrc + (kt) * BK); \
        ra0 = s_[0]; ra1 = s_[1]; \
        const float* w_ = wsrc + (size_t)(kt) * BK * HD; \
        _Pragma("unroll") \
        for (int j_ = 0; j_ < 8; j_++) rwv[j_] = w_[(size_t)j_ * HD]; \
    } while (0)

#define STORE2(buf) do { \
        *(uint4*)(sA[buf] + ar * 128 + (((acg * 2) ^ (ar & 7)) * 16)) = ra0; \
        *(uint4*)(sA[buf] + ar * 128 + (((acg * 2 + 1) ^ (ar & 7)) * 16)) = ra1; \
        *(uint4*)(sW[buf] + wc * 128 + ((whg ^ (wc & 7)) * 16)) = pack8f(rwv); \
    } while (0)

    f32x4 acc[2][2];
#pragma unroll
    for (int mb = 0; mb < 2; mb++)
#pragma unroll
        for (int cb = 0; cb < 2; cb++) acc[mb][cb] = (f32x4){0.f, 0.f, 0.f, 0.f};

    LOAD2(0);
    STORE2(0);
    __syncthreads();

    for (int kt = 0; kt < NKT; kt++) {
        const int cur = kt & 1;
        const bool more = (kt + 1 < NKT);
        if (more) LOAD2(kt + 1);
        const char* cA = sA[cur];
        const char* cW = sW[cur];
#pragma unroll
        for (int ks = 0; ks < 2; ks++) {
            const int s = ks * 4 + lk;
            bf16x8 af[2], wf[2];
#pragma unroll
            for (int mb = 0; mb < 2; mb++) {
                int rr = wm * 32 + mb * 16 + lr;
                af[mb] = *(const bf16x8*)(cA + rr * 128 + ((s ^ (rr & 7)) * 16));
            }
#pragma unroll
            for (int cb = 0; cb < 2; cb++) {
                int ii = wn * 32 + cb * 16 + lr;
                wf[cb] = *(const bf16x8*)(cW + ii * 128 + ((s ^ (ii & 7)) * 16));
            }
#pragma unroll
            for (int mb = 0; mb < 2; mb++)
#pragma unroll
                for (int cb = 0; cb < 2; cb++)
                    acc[mb][cb] = __builtin_amdgcn_mfma_f32_16x16x32_bf16(af[mb], wf[cb], acc[mb][cb], 0, 0, 0);
        }
        if (more) STORE2(cur ^ 1);
        __syncthreads();
    }
#undef LOAD2
#undef STORE2

#pragma unroll
    for (int mb = 0; mb < 2; mb++)
#pragma unroll
        for (int cb = 0; cb < 2; cb++) {
            const int col = h0 + wn * 32 + cb * 16 + lr;
            const float bdv = bd[e * HD + col];
#pragma unroll
            for (int q = 0; q < 4; q++) {
                const int r = wm * 32 + mb * 16 + lk * 4 + q;
                if (r < mcount) {
                    int idx = lidx[r];
                    float w = topw[idx];
                    atomicAdd(&out[(size_t)(idx >> 2) * HD + col], w * (acc[mb][cb][q] + bdv));
                }
            }
        }
}

extern "C" void kernel_launch(void* const* d_in, const int* in_sizes, int n_in,
                              void* d_out, int out_size, void* d_ws, size_t ws_size,
                              hipStream_t stream)
{
    const float* x  = (const float*)d_in[0];
    const float* rw = (const float*)d_in[1];
    const float* rb = (const float*)d_in[2];
    const float* wg = (const float*)d_in[3];
    const float* bg = (const float*)d_in[4];
    const float* wu = (const float*)d_in[5];
    const float* bu = (const float*)d_in[6];
    const float* wd = (const float*)d_in[7];
    const float* bd = (const float*)d_in[8];
    float* out = (float*)d_out;

    char* ws = (char*)d_ws;
    int*   cnt  = (int*)(ws + 0);
    int*   offs = (int*)(ws + 256);
    float* topw = (float*)(ws + 1024);
    int*   list = (int*)(ws + 32768);
    unsigned short* act = (unsigned short*)(ws + 131072); // 4096 x 2880 bf16

    hipLaunchKernelGGL(k_init, dim3(T_TOK * HD / 1024), dim3(256), 0, stream, out, cnt);
    hipLaunchKernelGGL(k_router, dim3(T_TOK), dim3(256), 0, stream, x, rw, rb, topw, cnt, list);
    hipLaunchKernelGGL(k_scan, dim3(1), dim3(64), 0, stream, cnt, offs);
    hipLaunchKernelGGL(k_gemm1, dim3(NB1), dim3(512), 0, stream,
                       x, wg, bg, wu, bu, cnt, offs, list, act);
    hipLaunchKernelGGL(k_gemm2, dim3(NB1), dim3(512), 0, stream,
                       act, wd, bd, topw, cnt, offs, list, out);
}